// Round 7
// baseline (127.038 us; speedup 1.0000x reference)
//
#include <hip/hip_runtime.h>

// Attention 8192x8192, D=DV=64, fp32 in/out.
// R7: R6 with a register-budget-correct pipeline: K double-buffered, V
// single-buffered (loaded one compute-phase ahead), VALU row-sums instead of
// ones-MFMA (frees 12 unified regs), waves_per_eu(4,4) to unlock the full
// 128-reg budget, sched_barrier(0) fences to stop prefetch-load sinking, and
// per-block tile-phase rotation to de-convoy L2. Prepass (fragment-linear
// bf16 K / V-transposed) unchanged from R6.

#define NQ 8192
#define NK 8192

typedef float f32x4 __attribute__((ext_vector_type(4)));
typedef short short8 __attribute__((ext_vector_type(8)));
union U4 { uint4 u; short8 s; };

#define MFMA16 __builtin_amdgcn_mfma_f32_16x16x32_bf16

// round-to-nearest-even fp32->bf16 pair pack (lo = a)
__device__ __forceinline__ unsigned pk2(float a, float b) {
    unsigned ua = __builtin_bit_cast(unsigned, a);
    unsigned ub = __builtin_bit_cast(unsigned, b);
    ua = (ua + 0x7FFFu + ((ua >> 16) & 1u)) >> 16;
    ub = (ub + 0x7FFFu + ((ub >> 16) & 1u)) & 0xFFFF0000u;
    return ua | ub;
}

// ---- prepass: swizzle K/V into fragment-linear bf16 layouts ----
// Kb4[(kc*4 + e*2 + h)*64 + i16*4 + q] = bf16x8 of K[kc*32 + 2*i16 + e][h*32+q*8 .. +8)
// Vt4[(kc*4 + dt)*64 + i16*4 + q]      = bf16x8 of V[kc*32 + q*8 .. +8)][dt*16+i16]
__global__ __launch_bounds__(256)
void prepass(const float* __restrict__ Kg, const float* __restrict__ Vg,
             uint4* __restrict__ Kb4, uint4* __restrict__ Vt4) {
    __shared__ float ld[64 * 33];
    const int t = threadIdx.x, b = blockIdx.x;   // b = key chunk (32 keys)

    {
        const int kl = t >> 3, dg = t & 7;
        const int e = kl & 1, i16 = kl >> 1, h = dg >> 2, q = dg & 3;
        const float* gp = Kg + (size_t)(b * 32 + kl) * 64 + dg * 8;
        float4 f0 = *(const float4*)gp;
        float4 f1 = *(const float4*)(gp + 4);
        uint4 o = make_uint4(pk2(f0.x, f0.y), pk2(f0.z, f0.w),
                             pk2(f1.x, f1.y), pk2(f1.z, f1.w));
        Kb4[(size_t)(b * 4 + e * 2 + h) * 64 + i16 * 4 + q] = o;
    }
    {
        const int key = t >> 3, dg = t & 7;
        const float* gp = Vg + (size_t)(b * 32 + key) * 64 + dg * 8;
        float4 f0 = *(const float4*)gp;
        float4 f1 = *(const float4*)(gp + 4);
        ld[(dg * 8 + 0) * 33 + key] = f0.x;
        ld[(dg * 8 + 1) * 33 + key] = f0.y;
        ld[(dg * 8 + 2) * 33 + key] = f0.z;
        ld[(dg * 8 + 3) * 33 + key] = f0.w;
        ld[(dg * 8 + 4) * 33 + key] = f1.x;
        ld[(dg * 8 + 5) * 33 + key] = f1.y;
        ld[(dg * 8 + 6) * 33 + key] = f1.z;
        ld[(dg * 8 + 7) * 33 + key] = f1.w;
    }
    __syncthreads();
    {
        const int dim = t >> 2, kq = t & 3;
        const int dt = dim >> 4, i16 = dim & 15;
        float v[8];
        #pragma unroll
        for (int j = 0; j < 8; ++j) v[j] = ld[dim * 33 + kq * 8 + j];
        uint4 o = make_uint4(pk2(v[0], v[1]), pk2(v[2], v[3]),
                             pk2(v[4], v[5]), pk2(v[6], v[7]));
        Vt4[(size_t)(b * 4 + dt) * 64 + i16 * 4 + kq] = o;
    }
}

// ---- main kernel ----
__global__ __launch_bounds__(1024)
__attribute__((amdgpu_waves_per_eu(4, 4)))
void attn_main(const float* __restrict__ Qg,
               const uint4* __restrict__ Kb4,
               const uint4* __restrict__ Vt4,
               float* __restrict__ Og) {
    // LDS: 8 merge regions x 2080 floats (66,560 B); first 2048 uint4 alias
    // as the 32 P regions ([w][rt] x 64 uint4) during the main loop.
    __shared__ uint4 shb4[4160];
    float* sF = (float*)shb4;
    unsigned* shu = (unsigned*)shb4;

    const int t = threadIdx.x, w = t >> 6, lane = t & 63;
    const int q = lane >> 4, i16 = lane & 15;
    const int qb0 = blockIdx.x * 32;
    const int lsl = i16 * 4 + q;             // lane-linear slot (0..63)
    const int phase = blockIdx.x & 15;       // tile-order rotation

    // Q fragments (scale 1/8 * log2 e folded)
    const float SCL = 0.18033688011112042f;
    short8 aq0, aq1, aq2, aq3;   // [rt][h]
    {
        const float* qp0 = Qg + (size_t)(qb0 + i16) * 64 + q * 8;
        const float* qp1 = Qg + (size_t)(qb0 + 16 + i16) * 64 + q * 8;
        U4 u;
        float4 f0, f1;
        f0 = *(const float4*)(qp0);      f1 = *(const float4*)(qp0 + 4);
        u.u = make_uint4(pk2(f0.x * SCL, f0.y * SCL), pk2(f0.z * SCL, f0.w * SCL),
                         pk2(f1.x * SCL, f1.y * SCL), pk2(f1.z * SCL, f1.w * SCL));
        aq0 = u.s;
        f0 = *(const float4*)(qp0 + 32); f1 = *(const float4*)(qp0 + 36);
        u.u = make_uint4(pk2(f0.x * SCL, f0.y * SCL), pk2(f0.z * SCL, f0.w * SCL),
                         pk2(f1.x * SCL, f1.y * SCL), pk2(f1.z * SCL, f1.w * SCL));
        aq1 = u.s;
        f0 = *(const float4*)(qp1);      f1 = *(const float4*)(qp1 + 4);
        u.u = make_uint4(pk2(f0.x * SCL, f0.y * SCL), pk2(f0.z * SCL, f0.w * SCL),
                         pk2(f1.x * SCL, f1.y * SCL), pk2(f1.z * SCL, f1.w * SCL));
        aq2 = u.s;
        f0 = *(const float4*)(qp1 + 32); f1 = *(const float4*)(qp1 + 36);
        u.u = make_uint4(pk2(f0.x * SCL, f0.y * SCL), pk2(f0.z * SCL, f0.w * SCL),
                         pk2(f1.x * SCL, f1.y * SCL), pk2(f1.z * SCL, f1.w * SCL));
        aq3 = u.s;
    }

    f32x4 acc[2][4];           // O accumulators (AGPR), static idx
    float lsum[2][4];          // per-lane row-sum partials (VALU)
    #pragma unroll
    for (int rt = 0; rt < 2; ++rt) {
        #pragma unroll
        for (int dt = 0; dt < 4; ++dt) { acc[rt][dt][0]=0.f; acc[rt][dt][1]=0.f; acc[rt][dt][2]=0.f; acc[rt][dt][3]=0.f; }
        #pragma unroll
        for (int r = 0; r < 4; ++r) lsum[rt][r] = 0.f;
    }

    // P slot indices (layout verified in R2-R6)
    const int tpw = ((i16 >> 2) & 1) + 2 * q + 32 * (i16 >> 3);  // tp = tpw + 8r
    const int pp  = i16 & 3;
    const int tpr = (q & 1) + 2 * ((i16 >> 2) & 3) + 8 * (i16 & 3) + 32 * (q >> 1);

    uint4 kfA[4], kfB[4], vf[4];
    U4 ap0, ap1;

#define LOAD_K(TT, KD)                                                               \
    do {                                                                             \
        const int cb = ((((TT) + phase) & 15) * 16 + w) * 4;                         \
        _Pragma("unroll")                                                            \
        for (int eh = 0; eh < 4; ++eh)                                               \
            (KD)[eh] = Kb4[(size_t)(cb + eh) * 64 + lsl];                            \
    } while (0)

#define LOAD_V(TT)                                                                   \
    do {                                                                             \
        const int cb = ((((TT) + phase) & 15) * 16 + w) * 4;                         \
        _Pragma("unroll")                                                            \
        for (int dt = 0; dt < 4; ++dt)                                               \
            vf[dt] = Vt4[(size_t)(cb + dt) * 64 + lsl];                              \
    } while (0)

    // QK -> exp2 -> pack P into LDS -> read A-frags; also VALU row-sum partials
#define QKEXP(KD)                                                                    \
    do {                                                                             \
        _Pragma("unroll")                                                            \
        for (int rt = 0; rt < 2; ++rt) {                                             \
            f32x4 s0, s1;                                                            \
            s0[0]=-16.f; s0[1]=-16.f; s0[2]=-16.f; s0[3]=-16.f;                      \
            s1[0]=-16.f; s1[1]=-16.f; s1[2]=-16.f; s1[3]=-16.f;                      \
            U4 u0, u1, u2, u3;                                                       \
            u0.u = (KD)[0]; u1.u = (KD)[1]; u2.u = (KD)[2]; u3.u = (KD)[3];          \
            s0 = MFMA16(rt ? aq2 : aq0, u0.s, s0, 0, 0, 0);                          \
            s0 = MFMA16(rt ? aq3 : aq1, u1.s, s0, 0, 0, 0);                          \
            s1 = MFMA16(rt ? aq2 : aq0, u2.s, s1, 0, 0, 0);                          \
            s1 = MFMA16(rt ? aq3 : aq1, u3.s, s1, 0, 0, 0);                          \
            const int rbase = (w * 2 + rt) * 256;                                    \
            _Pragma("unroll")                                                        \
            for (int r = 0; r < 4; ++r) {                                            \
                float p0 = __builtin_amdgcn_exp2f(s0[r]);                            \
                float p1 = __builtin_amdgcn_exp2f(s1[r]);                            \
                lsum[rt][r] += p0;                                                   \
                lsum[rt][r] += p1;                                                   \
                shu[rbase + (tpw + 8 * r) * 4 + pp] = pk2(p0, p1);                   \
            }                                                                        \
        }                                                                            \
        ap0.u = shb4[(w * 2 + 0) * 64 + tpr];                                        \
        ap1.u = shb4[(w * 2 + 1) * 64 + tpr];                                        \
    } while (0)

#define PV()                                                                         \
    do {                                                                             \
        _Pragma("unroll")                                                            \
        for (int dt = 0; dt < 4; ++dt) {                                             \
            U4 bv; bv.u = vf[dt];                                                    \
            acc[0][dt] = MFMA16(ap0.s, bv.s, acc[0][dt], 0, 0, 0);                   \
            acc[1][dt] = MFMA16(ap1.s, bv.s, acc[1][dt], 0, 0, 0);                   \
        }                                                                            \
    } while (0)

    LOAD_K(0, kfA);
    LOAD_V(0);
    #pragma unroll 1
    for (int tt = 0; tt < 16; tt += 2) {
        LOAD_K(tt + 1, kfB);
        __builtin_amdgcn_sched_barrier(0);
        QKEXP(kfA);
        PV();                 // vf = V(tt)
        LOAD_V(tt + 1);
        LOAD_K(tt + 2, kfA);  // (tt+2) wraps via &15 inside LOAD_K
        __builtin_amdgcn_sched_barrier(0);
        QKEXP(kfB);
        PV();                 // vf = V(tt+1)
        LOAD_V(tt + 2);
        __builtin_amdgcn_sched_barrier(0);
    }

    // ---- reduce row-sum partials across the 16 key-lanes of each quad ----
    #pragma unroll
    for (int rt = 0; rt < 2; ++rt)
        #pragma unroll
        for (int r = 0; r < 4; ++r) {
            float v = lsum[rt][r];
            v += __shfl_xor(v, 1);
            v += __shfl_xor(v, 2);
            v += __shfl_xor(v, 4);
            v += __shfl_xor(v, 8);
            lsum[rt][r] = v;   // uniform across the 16 lanes of quad q
        }

    // ---- tree-merge the 16 key-split partials ----
    __syncthreads();
    for (int step = 8; step >= 1; step >>= 1) {
        if (w >= step && w < 2 * step) {
            float* base = sF + (w - step) * 2080;
            #pragma unroll
            for (int rt = 0; rt < 2; ++rt) {
                #pragma unroll
                for (int dt = 0; dt < 4; ++dt)
                    #pragma unroll
                    for (int r = 0; r < 4; ++r)
                        base[(rt * 16 + 4 * q + r) * 64 + dt * 16 + i16] = acc[rt][dt][r];
                if (i16 == 0) {
                    #pragma unroll
                    for (int r = 0; r < 4; ++r) base[2048 + rt * 16 + 4 * q + r] = lsum[rt][r];
                }
            }
        }
        __syncthreads();
        if (w < step) {
            const float* base = sF + w * 2080;
            #pragma unroll
            for (int rt = 0; rt < 2; ++rt) {
                #pragma unroll
                for (int dt = 0; dt < 4; ++dt)
                    #pragma unroll
                    for (int r = 0; r < 4; ++r)
                        acc[rt][dt][r] += base[(rt * 16 + 4 * q + r) * 64 + dt * 16 + i16];
                #pragma unroll
                for (int r = 0; r < 4; ++r) lsum[rt][r] += base[2048 + rt * 16 + 4 * q + r];
            }
        }
        __syncthreads();
    }

    // wave 0 normalizes into LDS; first 512 threads store float4
    if (w == 0) {
        #pragma unroll
        for (int rt = 0; rt < 2; ++rt)
            #pragma unroll
            for (int r = 0; r < 4; ++r) {
                const float inv = 1.0f / lsum[rt][r];
                #pragma unroll
                for (int dt = 0; dt < 4; ++dt)
                    sF[(rt * 16 + 4 * q + r) * 64 + dt * 16 + i16] = acc[rt][dt][r] * inv;
            }
    }
    __syncthreads();
    if (t < 512) {
        const int row = t >> 4, ds = t & 15;
        float4 o = *(const float4*)(sF + row * 64 + ds * 4);
        *(float4*)(Og + (size_t)(qb0 + row) * 64 + ds * 4) = o;
    }
}

extern "C" void kernel_launch(void* const* d_in, const int* in_sizes, int n_in,
                              void* d_out, int out_size, void* d_ws, size_t ws_size,
                              hipStream_t stream) {
    const float* Q = (const float*)d_in[0];
    const float* K = (const float*)d_in[1];
    const float* V = (const float*)d_in[2];
    float* O = (float*)d_out;
    uint4* Kb4 = (uint4*)d_ws;                        // 1 MB, fragment-linear
    uint4* Vt4 = (uint4*)((char*)d_ws + (1 << 20));   // 1 MB, fragment-linear
    hipLaunchKernelGGL(prepass, dim3(256), dim3(256), 0, stream, K, V, Kb4, Vt4);
    hipLaunchKernelGGL(attn_main, dim3(NQ / 32), dim3(1024), 0, stream, Q, Kb4, Vt4, O);
}

// Round 8
// 97.028 us; speedup vs baseline: 1.3093x; 1.3093x over previous
//
#include <hip/hip_runtime.h>

// Attention 8192x8192, D=DV=64, fp32 in/out.
// R8: trade TLP for ILP. 512-thread blocks (2 waves/SIMD -> 256-reg budget),
// 3-buffer depth-2 software pipeline of direct-from-L2 fragment loads
// (fragment-linear bf16 K / V-transposed from prepass), sched_barrier fences,
// VALU row-sums, per-block tile-phase rotation. 8-way key split, 256-key
// tiles, 32 Q-rows/block, fixed-offset softmax.

#define NQ 8192
#define NK 8192

typedef float f32x4 __attribute__((ext_vector_type(4)));
typedef short short8 __attribute__((ext_vector_type(8)));
union U4 { uint4 u; short8 s; };

#define MFMA16 __builtin_amdgcn_mfma_f32_16x16x32_bf16

// round-to-nearest-even fp32->bf16 pair pack (lo = a)
__device__ __forceinline__ unsigned pk2(float a, float b) {
    unsigned ua = __builtin_bit_cast(unsigned, a);
    unsigned ub = __builtin_bit_cast(unsigned, b);
    ua = (ua + 0x7FFFu + ((ua >> 16) & 1u)) >> 16;
    ub = (ub + 0x7FFFu + ((ub >> 16) & 1u)) & 0xFFFF0000u;
    return ua | ub;
}

// ---- prepass: swizzle K/V into fragment-linear bf16 layouts ----
// Kb4[(kc*4 + e*2 + h)*64 + i16*4 + q] = bf16x8 of K[kc*32 + 2*i16 + e][h*32+q*8 .. +8)
// Vt4[(kc*4 + dt)*64 + i16*4 + q]      = bf16x8 of V[kc*32 + q*8 .. +8)][dt*16+i16]
// grid 512: blocks 0..255 convert K chunk b; blocks 256..511 V chunk b-256.
__global__ __launch_bounds__(256)
void prepass(const float* __restrict__ Kg, const float* __restrict__ Vg,
             uint4* __restrict__ Kb4, uint4* __restrict__ Vt4) {
    __shared__ float ld[64 * 33];
    const int t = threadIdx.x, b = blockIdx.x;

    if (b < 256) {
        const int kl = t >> 3, dg = t & 7;
        const int e = kl & 1, i16 = kl >> 1, h = dg >> 2, q = dg & 3;
        const float* gp = Kg + (size_t)(b * 32 + kl) * 64 + dg * 8;
        float4 f0 = *(const float4*)gp;
        float4 f1 = *(const float4*)(gp + 4);
        uint4 o = make_uint4(pk2(f0.x, f0.y), pk2(f0.z, f0.w),
                             pk2(f1.x, f1.y), pk2(f1.z, f1.w));
        Kb4[(size_t)(b * 4 + e * 2 + h) * 64 + i16 * 4 + q] = o;
    } else {
        const int c = b - 256;
        {
            const int key = t >> 3, dg = t & 7;
            const float* gp = Vg + (size_t)(c * 32 + key) * 64 + dg * 8;
            float4 f0 = *(const float4*)gp;
            float4 f1 = *(const float4*)(gp + 4);
            ld[(dg * 8 + 0) * 33 + key] = f0.x;
            ld[(dg * 8 + 1) * 33 + key] = f0.y;
            ld[(dg * 8 + 2) * 33 + key] = f0.z;
            ld[(dg * 8 + 3) * 33 + key] = f0.w;
            ld[(dg * 8 + 4) * 33 + key] = f1.x;
            ld[(dg * 8 + 5) * 33 + key] = f1.y;
            ld[(dg * 8 + 6) * 33 + key] = f1.z;
            ld[(dg * 8 + 7) * 33 + key] = f1.w;
        }
        __syncthreads();
        {
            const int dim = t >> 2, kq = t & 3;
            const int dt = dim >> 4, i16 = dim & 15;
            float v[8];
            #pragma unroll
            for (int j = 0; j < 8; ++j) v[j] = ld[dim * 33 + kq * 8 + j];
            uint4 o = make_uint4(pk2(v[0], v[1]), pk2(v[2], v[3]),
                                 pk2(v[4], v[5]), pk2(v[6], v[7]));
            Vt4[(size_t)(c * 4 + dt) * 64 + i16 * 4 + kq] = o;
        }
    }
}

// ---- main kernel ----
__global__ __launch_bounds__(512, 1)
void attn_main(const float* __restrict__ Qg,
               const uint4* __restrict__ Kb4,
               const uint4* __restrict__ Vt4,
               float* __restrict__ Og) {
    // LDS: 4 merge regions x 2080 floats (33,280 B); first 1024 uint4 alias
    // as the 16 P regions ([w][rt] x 64 uint4) during the main loop.
    __shared__ uint4 shb4[2080];
    float* sF = (float*)shb4;
    unsigned* shu = (unsigned*)shb4;

    const int t = threadIdx.x, w = t >> 6, lane = t & 63;
    const int q = lane >> 4, i16 = lane & 15;
    const int qb0 = blockIdx.x * 32;
    const int lsl = i16 * 4 + q;             // lane-linear slot (0..63)
    const int phase = blockIdx.x & 31;       // tile-order rotation (32 tiles)

    // Q fragments (scale 1/8 * log2 e folded)
    const float SCL = 0.18033688011112042f;
    short8 aq0, aq1, aq2, aq3;   // [rt][h]
    {
        const float* qp0 = Qg + (size_t)(qb0 + i16) * 64 + q * 8;
        const float* qp1 = Qg + (size_t)(qb0 + 16 + i16) * 64 + q * 8;
        U4 u;
        float4 f0, f1;
        f0 = *(const float4*)(qp0);      f1 = *(const float4*)(qp0 + 4);
        u.u = make_uint4(pk2(f0.x * SCL, f0.y * SCL), pk2(f0.z * SCL, f0.w * SCL),
                         pk2(f1.x * SCL, f1.y * SCL), pk2(f1.z * SCL, f1.w * SCL));
        aq0 = u.s;
        f0 = *(const float4*)(qp0 + 32); f1 = *(const float4*)(qp0 + 36);
        u.u = make_uint4(pk2(f0.x * SCL, f0.y * SCL), pk2(f0.z * SCL, f0.w * SCL),
                         pk2(f1.x * SCL, f1.y * SCL), pk2(f1.z * SCL, f1.w * SCL));
        aq1 = u.s;
        f0 = *(const float4*)(qp1);      f1 = *(const float4*)(qp1 + 4);
        u.u = make_uint4(pk2(f0.x * SCL, f0.y * SCL), pk2(f0.z * SCL, f0.w * SCL),
                         pk2(f1.x * SCL, f1.y * SCL), pk2(f1.z * SCL, f1.w * SCL));
        aq2 = u.s;
        f0 = *(const float4*)(qp1 + 32); f1 = *(const float4*)(qp1 + 36);
        u.u = make_uint4(pk2(f0.x * SCL, f0.y * SCL), pk2(f0.z * SCL, f0.w * SCL),
                         pk2(f1.x * SCL, f1.y * SCL), pk2(f1.z * SCL, f1.w * SCL));
        aq3 = u.s;
    }

    f32x4 acc[2][4];           // O accumulators, static idx
    float lsum[2][4];          // per-lane row-sum partials (VALU)
    #pragma unroll
    for (int rt = 0; rt < 2; ++rt) {
        #pragma unroll
        for (int dt = 0; dt < 4; ++dt) { acc[rt][dt][0]=0.f; acc[rt][dt][1]=0.f; acc[rt][dt][2]=0.f; acc[rt][dt][3]=0.f; }
        #pragma unroll
        for (int r = 0; r < 4; ++r) lsum[rt][r] = 0.f;
    }

    // P slot indices (layout verified in R2-R7)
    const int tpw = ((i16 >> 2) & 1) + 2 * q + 32 * (i16 >> 3);  // tp = tpw + 8r
    const int pp  = i16 & 3;
    const int tpr = (q & 1) + 2 * ((i16 >> 2) & 3) + 8 * (i16 & 3) + 32 * (q >> 1);

    uint4 kfA[4], vfA[4], kfB[4], vfB[4], kfC[4], vfC[4];

    // chunk base for wave w in tile TT (8 chunks/tile, 32 tiles)
#define LOAD_T(TT, KD, VD)                                                           \
    do {                                                                             \
        const int cb = ((((TT) + phase) & 31) * 8 + w) * 4;                          \
        _Pragma("unroll")                                                            \
        for (int eh = 0; eh < 4; ++eh)                                               \
            (KD)[eh] = Kb4[(size_t)(cb + eh) * 64 + lsl];                            \
        _Pragma("unroll")                                                            \
        for (int dt = 0; dt < 4; ++dt)                                               \
            (VD)[dt] = Vt4[(size_t)(cb + dt) * 64 + lsl];                            \
    } while (0)

#define COMPUTE(KD, VD)                                                              \
    do {                                                                             \
        U4 ap0, ap1;                                                                 \
        _Pragma("unroll")                                                            \
        for (int rt = 0; rt < 2; ++rt) {                                             \
            f32x4 s0, s1;                                                            \
            s0[0]=-16.f; s0[1]=-16.f; s0[2]=-16.f; s0[3]=-16.f;                      \
            s1[0]=-16.f; s1[1]=-16.f; s1[2]=-16.f; s1[3]=-16.f;                      \
            U4 u0, u1, u2, u3;                                                       \
            u0.u = (KD)[0]; u1.u = (KD)[1]; u2.u = (KD)[2]; u3.u = (KD)[3];          \
            s0 = MFMA16(rt ? aq2 : aq0, u0.s, s0, 0, 0, 0);                          \
            s0 = MFMA16(rt ? aq3 : aq1, u1.s, s0, 0, 0, 0);                          \
            s1 = MFMA16(rt ? aq2 : aq0, u2.s, s1, 0, 0, 0);                          \
            s1 = MFMA16(rt ? aq3 : aq1, u3.s, s1, 0, 0, 0);                          \
            const int rbase = (w * 2 + rt) * 256;                                    \
            _Pragma("unroll")                                                        \
            for (int r = 0; r < 4; ++r) {                                            \
                float p0 = __builtin_amdgcn_exp2f(s0[r]);                            \
                float p1 = __builtin_amdgcn_exp2f(s1[r]);                            \
                lsum[rt][r] += p0;                                                   \
                lsum[rt][r] += p1;                                                   \
                shu[rbase + (tpw + 8 * r) * 4 + pp] = pk2(p0, p1);                   \
            }                                                                        \
        }                                                                            \
        ap0.u = shb4[(w * 2 + 0) * 64 + tpr];                                        \
        ap1.u = shb4[(w * 2 + 1) * 64 + tpr];                                        \
        _Pragma("unroll")                                                            \
        for (int dt = 0; dt < 4; ++dt) {                                             \
            U4 bv; bv.u = (VD)[dt];                                                  \
            acc[0][dt] = MFMA16(ap0.s, bv.s, acc[0][dt], 0, 0, 0);                   \
            acc[1][dt] = MFMA16(ap1.s, bv.s, acc[1][dt], 0, 0, 0);                   \
        }                                                                            \
    } while (0)

    LOAD_T(0, kfA, vfA);
    LOAD_T(1, kfB, vfB);
    LOAD_T(2, kfC, vfC);
    __builtin_amdgcn_sched_barrier(0);
    #pragma unroll 1
    for (int tt = 0; tt < 30; tt += 3) {
        COMPUTE(kfA, vfA);
        LOAD_T(tt + 3, kfA, vfA);
        __builtin_amdgcn_sched_barrier(0);
        COMPUTE(kfB, vfB);
        LOAD_T(tt + 4, kfB, vfB);
        __builtin_amdgcn_sched_barrier(0);
        COMPUTE(kfC, vfC);
        LOAD_T(tt + 5, kfC, vfC);
        __builtin_amdgcn_sched_barrier(0);
    }
    COMPUTE(kfA, vfA);   // tile 30
    COMPUTE(kfB, vfB);   // tile 31

    // ---- reduce row-sum partials across the 16 key-lanes of each quad ----
    #pragma unroll
    for (int rt = 0; rt < 2; ++rt)
        #pragma unroll
        for (int r = 0; r < 4; ++r) {
            float v = lsum[rt][r];
            v += __shfl_xor(v, 1);
            v += __shfl_xor(v, 2);
            v += __shfl_xor(v, 4);
            v += __shfl_xor(v, 8);
            lsum[rt][r] = v;   // uniform across the 16 lanes of quad q
        }

    // ---- tree-merge the 8 key-split partials ----
    __syncthreads();
    for (int step = 4; step >= 1; step >>= 1) {
        if (w >= step && w < 2 * step) {
            float* base = sF + (w - step) * 2080;
            #pragma unroll
            for (int rt = 0; rt < 2; ++rt) {
                #pragma unroll
                for (int dt = 0; dt < 4; ++dt)
                    #pragma unroll
                    for (int r = 0; r < 4; ++r)
                        base[(rt * 16 + 4 * q + r) * 64 + dt * 16 + i16] = acc[rt][dt][r];
                if (i16 == 0) {
                    #pragma unroll
                    for (int r = 0; r < 4; ++r) base[2048 + rt * 16 + 4 * q + r] = lsum[rt][r];
                }
            }
        }
        __syncthreads();
        if (w < step) {
            const float* base = sF + w * 2080;
            #pragma unroll
            for (int rt = 0; rt < 2; ++rt) {
                #pragma unroll
                for (int dt = 0; dt < 4; ++dt)
                    #pragma unroll
                    for (int r = 0; r < 4; ++r)
                        acc[rt][dt][r] += base[(rt * 16 + 4 * q + r) * 64 + dt * 16 + i16];
                #pragma unroll
                for (int r = 0; r < 4; ++r) lsum[rt][r] += base[2048 + rt * 16 + 4 * q + r];
            }
        }
        __syncthreads();
    }

    // wave 0 normalizes into LDS; all 512 threads store float4
    if (w == 0) {
        #pragma unroll
        for (int rt = 0; rt < 2; ++rt)
            #pragma unroll
            for (int r = 0; r < 4; ++r) {
                const float inv = 1.0f / lsum[rt][r];
                #pragma unroll
                for (int dt = 0; dt < 4; ++dt)
                    sF[(rt * 16 + 4 * q + r) * 64 + dt * 16 + i16] = acc[rt][dt][r] * inv;
            }
    }
    __syncthreads();
    {
        const int row = t >> 4, ds = t & 15;
        float4 o = *(const float4*)(sF + row * 64 + ds * 4);
        *(float4*)(Og + (size_t)(qb0 + row) * 64 + ds * 4) = o;
    }
}

extern "C" void kernel_launch(void* const* d_in, const int* in_sizes, int n_in,
                              void* d_out, int out_size, void* d_ws, size_t ws_size,
                              hipStream_t stream) {
    const float* Q = (const float*)d_in[0];
    const float* K = (const float*)d_in[1];
    const float* V = (const float*)d_in[2];
    float* O = (float*)d_out;
    uint4* Kb4 = (uint4*)d_ws;                        // 1 MB, fragment-linear
    uint4* Vt4 = (uint4*)((char*)d_ws + (1 << 20));   // 1 MB, fragment-linear
    hipLaunchKernelGGL(prepass, dim3(512), dim3(256), 0, stream, K, V, Kb4, Vt4);
    hipLaunchKernelGGL(attn_main, dim3(NQ / 32), dim3(512), 0, stream, Q, Kb4, Vt4, O);
}

// Round 9
// 93.526 us; speedup vs baseline: 1.3583x; 1.0374x over previous
//
#include <hip/hip_runtime.h>

// Attention 8192x8192, D=DV=64, fp32 in/out.
// R9: cut the L2-path byte wall. 64 Q-rows x 4096 keys per block (grid 256 =
// 128 row-groups x 2 key-halves) halves per-CU K/V traffic vs R8. Fixed-offset
// softmax makes key-half partials plain-summable: blocks write unnormalized
// (O,l) to d_ws; a small merge kernel sums + normalizes. Fragment-linear bf16
// K/Vt prepass, 2-buffer pipelined direct-from-L2 fragment loads, VALU row
// sums, per-wave P LDS round-trip, 3-round in-block merge tree.

#define NQ 8192
#define NK 8192

typedef float f32x4 __attribute__((ext_vector_type(4)));
typedef short short8 __attribute__((ext_vector_type(8)));
union U4 { uint4 u; short8 s; };

#define MFMA16 __builtin_amdgcn_mfma_f32_16x16x32_bf16

// round-to-nearest-even fp32->bf16 pair pack (lo = a)
__device__ __forceinline__ unsigned pk2(float a, float b) {
    unsigned ua = __builtin_bit_cast(unsigned, a);
    unsigned ub = __builtin_bit_cast(unsigned, b);
    ua = (ua + 0x7FFFu + ((ua >> 16) & 1u)) >> 16;
    ub = (ub + 0x7FFFu + ((ub >> 16) & 1u)) & 0xFFFF0000u;
    return ua | ub;
}

// ---- prepass: swizzle K/V into fragment-linear bf16 layouts ----
// Kb4[(kc*4 + e*2 + h)*64 + i16*4 + q] = bf16x8 of K[kc*32 + 2*i16 + e][h*32+q*8 .. +8)
// Vt4[(kc*4 + dt)*64 + i16*4 + q]      = bf16x8 of V[kc*32 + q*8 .. +8)][dt*16+i16]
__global__ __launch_bounds__(256)
void prepass(const float* __restrict__ Kg, const float* __restrict__ Vg,
             uint4* __restrict__ Kb4, uint4* __restrict__ Vt4) {
    __shared__ float ld[64 * 33];
    const int t = threadIdx.x, b = blockIdx.x;

    if (b < 256) {
        const int kl = t >> 3, dg = t & 7;
        const int e = kl & 1, i16 = kl >> 1, h = dg >> 2, q = dg & 3;
        const float* gp = Kg + (size_t)(b * 32 + kl) * 64 + dg * 8;
        float4 f0 = *(const float4*)gp;
        float4 f1 = *(const float4*)(gp + 4);
        uint4 o = make_uint4(pk2(f0.x, f0.y), pk2(f0.z, f0.w),
                             pk2(f1.x, f1.y), pk2(f1.z, f1.w));
        Kb4[(size_t)(b * 4 + e * 2 + h) * 64 + i16 * 4 + q] = o;
    } else {
        const int c = b - 256;
        {
            const int key = t >> 3, dg = t & 7;
            const float* gp = Vg + (size_t)(c * 32 + key) * 64 + dg * 8;
            float4 f0 = *(const float4*)gp;
            float4 f1 = *(const float4*)(gp + 4);
            ld[(dg * 8 + 0) * 33 + key] = f0.x;
            ld[(dg * 8 + 1) * 33 + key] = f0.y;
            ld[(dg * 8 + 2) * 33 + key] = f0.z;
            ld[(dg * 8 + 3) * 33 + key] = f0.w;
            ld[(dg * 8 + 4) * 33 + key] = f1.x;
            ld[(dg * 8 + 5) * 33 + key] = f1.y;
            ld[(dg * 8 + 6) * 33 + key] = f1.z;
            ld[(dg * 8 + 7) * 33 + key] = f1.w;
        }
        __syncthreads();
        {
            const int dim = t >> 2, kq = t & 3;
            const int dt = dim >> 4, i16 = dim & 15;
            float v[8];
            #pragma unroll
            for (int j = 0; j < 8; ++j) v[j] = ld[dim * 33 + kq * 8 + j];
            uint4 o = make_uint4(pk2(v[0], v[1]), pk2(v[2], v[3]),
                                 pk2(v[4], v[5]), pk2(v[6], v[7]));
            Vt4[(size_t)(c * 4 + dt) * 64 + i16 * 4 + kq] = o;
        }
    }
}

// ---- main kernel: 64 rows x 4096 keys per block, writes (O,l) partials ----
__global__ __launch_bounds__(512, 1)
void attn_main(const float* __restrict__ Qg,
               const uint4* __restrict__ Kb4,
               const uint4* __restrict__ Vt4,
               float* __restrict__ Opart,
               float* __restrict__ Lpart) {
    // LDS: 4 merge regions x 4160 floats (66,560 B); first 2048 uint4 alias
    // as the 32 P regions ([w][rt] x 64 uint4) during the main loop.
    __shared__ uint4 shb4[4160];
    float* sF = (float*)shb4;
    unsigned* shu = (unsigned*)shb4;

    const int t = threadIdx.x, w = t >> 6, lane = t & 63;
    const int q = lane >> 4, i16 = lane & 15;
    const int bid = blockIdx.x;
    const int kh = bid & 1;          // key half 0/1
    const int rg = bid >> 1;         // row group 0..127
    const int qb0 = rg * 64;
    const int lsl = i16 * 4 + q;     // lane-linear slot (0..63)
    const int phase = rg & 15;       // tile-order rotation (16 tiles)

    // Q fragments: 4 row-tiles (scale 1/8 * log2 e folded)
    const float SCL = 0.18033688011112042f;
    short8 aq[4][2];
    #pragma unroll
    for (int rt = 0; rt < 4; ++rt) {
        const float* qp = Qg + (size_t)(qb0 + rt * 16 + i16) * 64 + q * 8;
        float4 f0 = *(const float4*)(qp);
        float4 f1 = *(const float4*)(qp + 4);
        U4 u;
        u.u = make_uint4(pk2(f0.x * SCL, f0.y * SCL), pk2(f0.z * SCL, f0.w * SCL),
                         pk2(f1.x * SCL, f1.y * SCL), pk2(f1.z * SCL, f1.w * SCL));
        aq[rt][0] = u.s;
        f0 = *(const float4*)(qp + 32);
        f1 = *(const float4*)(qp + 36);
        u.u = make_uint4(pk2(f0.x * SCL, f0.y * SCL), pk2(f0.z * SCL, f0.w * SCL),
                         pk2(f1.x * SCL, f1.y * SCL), pk2(f1.z * SCL, f1.w * SCL));
        aq[rt][1] = u.s;
    }

    f32x4 acc[4][4];           // O partial accumulators, static idx
    float lsum[4][4];          // per-lane row-sum partials (VALU)
    #pragma unroll
    for (int rt = 0; rt < 4; ++rt) {
        #pragma unroll
        for (int dt = 0; dt < 4; ++dt) { acc[rt][dt][0]=0.f; acc[rt][dt][1]=0.f; acc[rt][dt][2]=0.f; acc[rt][dt][3]=0.f; }
        #pragma unroll
        for (int r = 0; r < 4; ++r) lsum[rt][r] = 0.f;
    }

    // P slot indices (layout verified in R2-R8)
    const int tpw = ((i16 >> 2) & 1) + 2 * q + 32 * (i16 >> 3);  // tp = tpw + 8r
    const int pp  = i16 & 3;
    const int tpr = (q & 1) + 2 * ((i16 >> 2) & 3) + 8 * (i16 & 3) + 32 * (q >> 1);

    uint4 kfA[4], vfA[4], kfB[4], vfB[4];

    // chunk base for wave w in tile TT (8 chunks/tile, 16 tiles, key-half kh)
#define LOAD_T(TT, KD, VD)                                                           \
    do {                                                                             \
        const int cb = ((kh << 7) + ((((TT) + phase) & 15) * 8 + w)) * 4;            \
        _Pragma("unroll")                                                            \
        for (int eh = 0; eh < 4; ++eh)                                               \
            (KD)[eh] = Kb4[(size_t)(cb + eh) * 64 + lsl];                            \
        _Pragma("unroll")                                                            \
        for (int dt = 0; dt < 4; ++dt)                                               \
            (VD)[dt] = Vt4[(size_t)(cb + dt) * 64 + lsl];                            \
    } while (0)

#define COMPUTE(KD, VD)                                                              \
    do {                                                                             \
        U4 ap[4];                                                                    \
        _Pragma("unroll")                                                            \
        for (int rt = 0; rt < 4; ++rt) {                                             \
            f32x4 s0, s1;                                                            \
            s0[0]=-16.f; s0[1]=-16.f; s0[2]=-16.f; s0[3]=-16.f;                      \
            s1[0]=-16.f; s1[1]=-16.f; s1[2]=-16.f; s1[3]=-16.f;                      \
            U4 u0, u1, u2, u3;                                                       \
            u0.u = (KD)[0]; u1.u = (KD)[1]; u2.u = (KD)[2]; u3.u = (KD)[3];          \
            s0 = MFMA16(aq[rt][0], u0.s, s0, 0, 0, 0);                               \
            s0 = MFMA16(aq[rt][1], u1.s, s0, 0, 0, 0);                               \
            s1 = MFMA16(aq[rt][0], u2.s, s1, 0, 0, 0);                               \
            s1 = MFMA16(aq[rt][1], u3.s, s1, 0, 0, 0);                               \
            const int rbase = (w * 4 + rt) * 256;                                    \
            _Pragma("unroll")                                                        \
            for (int r = 0; r < 4; ++r) {                                            \
                float p0 = __builtin_amdgcn_exp2f(s0[r]);                            \
                float p1 = __builtin_amdgcn_exp2f(s1[r]);                            \
                lsum[rt][r] += p0;                                                   \
                lsum[rt][r] += p1;                                                   \
                shu[rbase + (tpw + 8 * r) * 4 + pp] = pk2(p0, p1);                   \
            }                                                                        \
        }                                                                            \
        _Pragma("unroll")                                                            \
        for (int rt = 0; rt < 4; ++rt) ap[rt].u = shb4[(w * 4 + rt) * 64 + tpr];     \
        _Pragma("unroll")                                                            \
        for (int dt = 0; dt < 4; ++dt) {                                             \
            U4 bv; bv.u = (VD)[dt];                                                  \
            _Pragma("unroll")                                                        \
            for (int rt = 0; rt < 4; ++rt)                                           \
                acc[rt][dt] = MFMA16(ap[rt].s, bv.s, acc[rt][dt], 0, 0, 0);          \
        }                                                                            \
    } while (0)

    LOAD_T(0, kfA, vfA);
    #pragma unroll 1
    for (int tt = 0; tt < 16; tt += 2) {
        LOAD_T(tt + 1, kfB, vfB);
        __builtin_amdgcn_sched_barrier(0);
        COMPUTE(kfA, vfA);
        LOAD_T((tt + 2) & 15, kfA, vfA);   // wraps once at the end (harmless)
        __builtin_amdgcn_sched_barrier(0);
        COMPUTE(kfB, vfB);
        __builtin_amdgcn_sched_barrier(0);
    }

    // ---- reduce row-sum partials across the 16 key-lanes of each quad ----
    #pragma unroll
    for (int rt = 0; rt < 4; ++rt)
        #pragma unroll
        for (int r = 0; r < 4; ++r) {
            float v = lsum[rt][r];
            v += __shfl_xor(v, 1);
            v += __shfl_xor(v, 2);
            v += __shfl_xor(v, 4);
            v += __shfl_xor(v, 8);
            lsum[rt][r] = v;   // uniform across the 16 lanes of quad q
        }

    // ---- tree-merge the 8 key-split partials (regions: 4160 floats) ----
    __syncthreads();
    for (int step = 4; step >= 1; step >>= 1) {
        if (w >= step && w < 2 * step) {
            float* base = sF + (w - step) * 4160;
            #pragma unroll
            for (int rt = 0; rt < 4; ++rt) {
                #pragma unroll
                for (int dt = 0; dt < 4; ++dt)
                    #pragma unroll
                    for (int r = 0; r < 4; ++r)
                        base[(rt * 16 + 4 * q + r) * 64 + dt * 16 + i16] = acc[rt][dt][r];
                if (i16 == 0) {
                    #pragma unroll
                    for (int r = 0; r < 4; ++r) base[4096 + rt * 16 + 4 * q + r] = lsum[rt][r];
                }
            }
        }
        __syncthreads();
        if (w < step) {
            const float* base = sF + w * 4160;
            #pragma unroll
            for (int rt = 0; rt < 4; ++rt) {
                #pragma unroll
                for (int dt = 0; dt < 4; ++dt)
                    #pragma unroll
                    for (int r = 0; r < 4; ++r)
                        acc[rt][dt][r] += base[(rt * 16 + 4 * q + r) * 64 + dt * 16 + i16];
                #pragma unroll
                for (int r = 0; r < 4; ++r) lsum[rt][r] += base[4096 + rt * 16 + 4 * q + r];
            }
        }
        __syncthreads();
    }

    // ---- wave 0 writes the block's (O,l) partial to global ----
    if (w == 0) {
        #pragma unroll
        for (int rt = 0; rt < 4; ++rt) {
            #pragma unroll
            for (int dt = 0; dt < 4; ++dt)
                #pragma unroll
                for (int r = 0; r < 4; ++r) {
                    const int row = qb0 + rt * 16 + 4 * q + r;
                    Opart[((size_t)kh * 8192 + row) * 64 + dt * 16 + i16] = acc[rt][dt][r];
                }
            if (i16 == 0) {
                #pragma unroll
                for (int r = 0; r < 4; ++r)
                    Lpart[kh * 8192 + qb0 + rt * 16 + 4 * q + r] = lsum[rt][r];
            }
        }
    }
}

// ---- merge: O = (O0 + O1) / (l0 + l1) ----
__global__ __launch_bounds__(256)
void merge(const float* __restrict__ Opart, const float* __restrict__ Lpart,
           float* __restrict__ Og) {
    const int idx = blockIdx.x * 256 + threadIdx.x;   // 0..131071
    const int row = idx >> 4, seg = idx & 15;
    const float4 a = *(const float4*)(Opart + (size_t)row * 64 + seg * 4);
    const float4 b = *(const float4*)(Opart + ((size_t)8192 + row) * 64 + seg * 4);
    const float inv = 1.0f / (Lpart[row] + Lpart[8192 + row]);
    float4 o;
    o.x = (a.x + b.x) * inv;
    o.y = (a.y + b.y) * inv;
    o.z = (a.z + b.z) * inv;
    o.w = (a.w + b.w) * inv;
    *(float4*)(Og + (size_t)row * 64 + seg * 4) = o;
}

extern "C" void kernel_launch(void* const* d_in, const int* in_sizes, int n_in,
                              void* d_out, int out_size, void* d_ws, size_t ws_size,
                              hipStream_t stream) {
    const float* Q = (const float*)d_in[0];
    const float* K = (const float*)d_in[1];
    const float* V = (const float*)d_in[2];
    float* O = (float*)d_out;
    char* ws = (char*)d_ws;
    uint4* Kb4   = (uint4*)ws;                        // 1 MB, fragment-linear
    uint4* Vt4   = (uint4*)(ws + (1 << 20));          // 1 MB, fragment-linear
    float* Opart = (float*)(ws + (2 << 20));          // 2 x 8192 x 64 fp32 = 4 MB
    float* Lpart = (float*)(ws + (6 << 20));          // 2 x 8192 fp32
    hipLaunchKernelGGL(prepass, dim3(512), dim3(256), 0, stream, K, V, Kb4, Vt4);
    hipLaunchKernelGGL(attn_main, dim3(256), dim3(512), 0, stream, Q, Kb4, Vt4, Opart, Lpart);
    hipLaunchKernelGGL(merge, dim3(512), dim3(256), 0, stream, Opart, Lpart, O);
}

// Round 10
// 89.106 us; speedup vs baseline: 1.4257x; 1.0496x over previous
//
#include <hip/hip_runtime.h>

// Attention 8192x8192, D=DV=64, fp32 in/out.
// R10: two-stage cross-chunk pipeline. Per iteration: QKEXP(t) and PV(t-1)
// run as independent streams (double-buffered per-wave P regions in LDS), so
// QK-MFMA / exp2-VALU / LDS / PV-MFMA co-schedule instead of serializing.
// P pack uses 1-op v_perm truncation (was 6-op RNE). 64 rows x 4096 keys per
// block (grid 256 = 128 rg x 2 kh), fragment-linear bf16 K/Vt prepass,
// unnormalized (O,l) partials + tiny merge kernel. Fixed-offset softmax.

#define NQ 8192
#define NK 8192

typedef float f32x4 __attribute__((ext_vector_type(4)));
typedef short short8 __attribute__((ext_vector_type(8)));
union U4 { uint4 u; short8 s; };

#define MFMA16 __builtin_amdgcn_mfma_f32_16x16x32_bf16

// round-to-nearest-even fp32->bf16 pair pack (lo = a) — used in prepass/Q only
__device__ __forceinline__ unsigned pk2(float a, float b) {
    unsigned ua = __builtin_bit_cast(unsigned, a);
    unsigned ub = __builtin_bit_cast(unsigned, b);
    ua = (ua + 0x7FFFu + ((ua >> 16) & 1u)) >> 16;
    ub = (ub + 0x7FFFu + ((ub >> 16) & 1u)) & 0xFFFF0000u;
    return ua | ub;
}

// 1-op truncation pack: dst = {hi16(b), hi16(a)} (lo = a)
__device__ __forceinline__ unsigned pkt(float a, float b) {
    return __builtin_amdgcn_perm(__builtin_bit_cast(unsigned, b),
                                 __builtin_bit_cast(unsigned, a), 0x07060302u);
}

// ---- prepass: swizzle K/V into fragment-linear bf16 layouts ----
__global__ __launch_bounds__(256)
void prepass(const float* __restrict__ Kg, const float* __restrict__ Vg,
             uint4* __restrict__ Kb4, uint4* __restrict__ Vt4) {
    __shared__ float ld[64 * 33];
    const int t = threadIdx.x, b = blockIdx.x;

    if (b < 256) {
        const int kl = t >> 3, dg = t & 7;
        const int e = kl & 1, i16 = kl >> 1, h = dg >> 2, q = dg & 3;
        const float* gp = Kg + (size_t)(b * 32 + kl) * 64 + dg * 8;
        float4 f0 = *(const float4*)gp;
        float4 f1 = *(const float4*)(gp + 4);
        uint4 o = make_uint4(pk2(f0.x, f0.y), pk2(f0.z, f0.w),
                             pk2(f1.x, f1.y), pk2(f1.z, f1.w));
        Kb4[(size_t)(b * 4 + e * 2 + h) * 64 + i16 * 4 + q] = o;
    } else {
        const int c = b - 256;
        {
            const int key = t >> 3, dg = t & 7;
            const float* gp = Vg + (size_t)(c * 32 + key) * 64 + dg * 8;
            float4 f0 = *(const float4*)gp;
            float4 f1 = *(const float4*)(gp + 4);
            ld[(dg * 8 + 0) * 33 + key] = f0.x;
            ld[(dg * 8 + 1) * 33 + key] = f0.y;
            ld[(dg * 8 + 2) * 33 + key] = f0.z;
            ld[(dg * 8 + 3) * 33 + key] = f0.w;
            ld[(dg * 8 + 4) * 33 + key] = f1.x;
            ld[(dg * 8 + 5) * 33 + key] = f1.y;
            ld[(dg * 8 + 6) * 33 + key] = f1.z;
            ld[(dg * 8 + 7) * 33 + key] = f1.w;
        }
        __syncthreads();
        {
            const int dim = t >> 2, kq = t & 3;
            const int dt = dim >> 4, i16 = dim & 15;
            float v[8];
            #pragma unroll
            for (int j = 0; j < 8; ++j) v[j] = ld[dim * 33 + kq * 8 + j];
            uint4 o = make_uint4(pk2(v[0], v[1]), pk2(v[2], v[3]),
                                 pk2(v[4], v[5]), pk2(v[6], v[7]));
            Vt4[(size_t)(c * 4 + dt) * 64 + i16 * 4 + kq] = o;
        }
    }
}

// ---- main kernel: 64 rows x 4096 keys per block, writes (O,l) partials ----
__global__ __launch_bounds__(512, 1)
void attn_main(const float* __restrict__ Qg,
               const uint4* __restrict__ Kb4,
               const uint4* __restrict__ Vt4,
               float* __restrict__ Opart,
               float* __restrict__ Lpart) {
    // LDS: P regions [w 0..7][rt 0..3][par 0..1] x 64 uint4 = 4096 uint4 (64KB)
    // during the loop; 4 merge regions x 4160 floats (66,560 B) after.
    __shared__ uint4 shb4[4160];
    float* sF = (float*)shb4;
    unsigned* shu = (unsigned*)shb4;

    const int t = threadIdx.x, w = t >> 6, lane = t & 63;
    const int q = lane >> 4, i16 = lane & 15;
    const int bid = blockIdx.x;
    const int kh = bid & 1;          // key half 0/1
    const int rg = bid >> 1;         // row group 0..127
    const int qb0 = rg * 64;
    const int lsl = i16 * 4 + q;     // lane-linear slot (0..63)
    const int phase = rg & 15;       // tile-order rotation (16 tiles)

    // Q fragments: 4 row-tiles (scale 1/8 * log2 e folded)
    const float SCL = 0.18033688011112042f;
    short8 aq[4][2];
    #pragma unroll
    for (int rt = 0; rt < 4; ++rt) {
        const float* qp = Qg + (size_t)(qb0 + rt * 16 + i16) * 64 + q * 8;
        float4 f0 = *(const float4*)(qp);
        float4 f1 = *(const float4*)(qp + 4);
        U4 u;
        u.u = make_uint4(pk2(f0.x * SCL, f0.y * SCL), pk2(f0.z * SCL, f0.w * SCL),
                         pk2(f1.x * SCL, f1.y * SCL), pk2(f1.z * SCL, f1.w * SCL));
        aq[rt][0] = u.s;
        f0 = *(const float4*)(qp + 32);
        f1 = *(const float4*)(qp + 36);
        u.u = make_uint4(pk2(f0.x * SCL, f0.y * SCL), pk2(f0.z * SCL, f0.w * SCL),
                         pk2(f1.x * SCL, f1.y * SCL), pk2(f1.z * SCL, f1.w * SCL));
        aq[rt][1] = u.s;
    }

    f32x4 acc[4][4];           // O partial accumulators, static idx
    float lsum[4][4];          // per-lane row-sum partials (VALU)
    #pragma unroll
    for (int rt = 0; rt < 4; ++rt) {
        #pragma unroll
        for (int dt = 0; dt < 4; ++dt) { acc[rt][dt][0]=0.f; acc[rt][dt][1]=0.f; acc[rt][dt][2]=0.f; acc[rt][dt][3]=0.f; }
        #pragma unroll
        for (int r = 0; r < 4; ++r) lsum[rt][r] = 0.f;
    }

    // P slot indices (layout verified in R2-R9)
    const int tpw = ((i16 >> 2) & 1) + 2 * q + 32 * (i16 >> 3);  // tp = tpw + 8r
    const int pp  = i16 & 3;
    const int tpr = (q & 1) + 2 * ((i16 >> 2) & 3) + 8 * (i16 & 3) + 32 * (q >> 1);

    uint4 kfA[4], vfA[4], kfB[4], vfB[4];

    // chunk base for wave w in tile TT (8 chunks/tile, 16 tiles, key-half kh)
#define LOAD_T(TT, KD, VD)                                                           \
    do {                                                                             \
        const int cb = ((kh << 7) + ((((TT) + phase) & 15) * 8 + w)) * 4;            \
        _Pragma("unroll")                                                            \
        for (int eh = 0; eh < 4; ++eh)                                               \
            (KD)[eh] = Kb4[(size_t)(cb + eh) * 64 + lsl];                            \
        _Pragma("unroll")                                                            \
        for (int dt = 0; dt < 4; ++dt)                                               \
            (VD)[dt] = Vt4[(size_t)(cb + dt) * 64 + lsl];                            \
    } while (0)

    // stage 1: QK^T -> exp2 -> truncation-pack P into region PAR
#define QKEXP(KD, PAR)                                                               \
    do {                                                                             \
        _Pragma("unroll")                                                            \
        for (int rt = 0; rt < 4; ++rt) {                                             \
            f32x4 s0, s1;                                                            \
            s0[0]=-16.f; s0[1]=-16.f; s0[2]=-16.f; s0[3]=-16.f;                      \
            s1[0]=-16.f; s1[1]=-16.f; s1[2]=-16.f; s1[3]=-16.f;                      \
            U4 u0, u1, u2, u3;                                                       \
            u0.u = (KD)[0]; u1.u = (KD)[1]; u2.u = (KD)[2]; u3.u = (KD)[3];          \
            s0 = MFMA16(aq[rt][0], u0.s, s0, 0, 0, 0);                               \
            s0 = MFMA16(aq[rt][1], u1.s, s0, 0, 0, 0);                               \
            s1 = MFMA16(aq[rt][0], u2.s, s1, 0, 0, 0);                               \
            s1 = MFMA16(aq[rt][1], u3.s, s1, 0, 0, 0);                               \
            const int rbase = (((w * 4 + rt) * 2) + (PAR)) * 256;                    \
            _Pragma("unroll")                                                        \
            for (int r = 0; r < 4; ++r) {                                            \
                float p0 = __builtin_amdgcn_exp2f(s0[r]);                            \
                float p1 = __builtin_amdgcn_exp2f(s1[r]);                            \
                lsum[rt][r] += p0;                                                   \
                lsum[rt][r] += p1;                                                   \
                shu[rbase + (tpw + 8 * r) * 4 + pp] = pkt(p0, p1);                   \
            }                                                                        \
        }                                                                            \
    } while (0)

    // stage 2: read P A-frags from region PAR, PV MFMA
#define PVS(VD, PAR)                                                                 \
    do {                                                                             \
        U4 ap[4];                                                                    \
        _Pragma("unroll")                                                            \
        for (int rt = 0; rt < 4; ++rt)                                               \
            ap[rt].u = shb4[(((w * 4 + rt) * 2) + (PAR)) * 64 + tpr];                \
        _Pragma("unroll")                                                            \
        for (int dt = 0; dt < 4; ++dt) {                                             \
            U4 bv; bv.u = (VD)[dt];                                                  \
            _Pragma("unroll")                                                        \
            for (int rt = 0; rt < 4; ++rt)                                           \
                acc[rt][dt] = MFMA16(ap[rt].s, bv.s, acc[rt][dt], 0, 0, 0);          \
        }                                                                            \
    } while (0)

    // ---- pipelined main loop: QKEXP(t) || PV(t-1) ----
    LOAD_T(0, kfA, vfA);
    LOAD_T(1, kfB, vfB);
    QKEXP(kfA, 0);                        // t = 0
    #pragma unroll 1
    for (int tt = 1; tt < 15; tt += 2) {
        // t = tt (odd): kfB/par1, PV(t-1) from vfA/par0, refill A with t+1
        QKEXP(kfB, 1);
        PVS(vfA, 0);
        LOAD_T(tt + 1, kfA, vfA);
        // t = tt+1 (even): kfA/par0, PV(t) from vfB/par1, refill B with t+2
        QKEXP(kfA, 0);
        PVS(vfB, 1);
        LOAD_T(tt + 2, kfB, vfB);
        __builtin_amdgcn_sched_barrier(0);
    }
    QKEXP(kfB, 1);                        // t = 15
    PVS(vfA, 0);                          // PV(14)
    PVS(vfB, 1);                          // PV(15)

    // ---- reduce row-sum partials across the 16 key-lanes of each quad ----
    #pragma unroll
    for (int rt = 0; rt < 4; ++rt)
        #pragma unroll
        for (int r = 0; r < 4; ++r) {
            float v = lsum[rt][r];
            v += __shfl_xor(v, 1);
            v += __shfl_xor(v, 2);
            v += __shfl_xor(v, 4);
            v += __shfl_xor(v, 8);
            lsum[rt][r] = v;   // uniform across the 16 lanes of quad q
        }

    // ---- tree-merge the 8 key-split partials (regions: 4160 floats) ----
    __syncthreads();
    for (int step = 4; step >= 1; step >>= 1) {
        if (w >= step && w < 2 * step) {
            float* base = sF + (w - step) * 4160;
            #pragma unroll
            for (int rt = 0; rt < 4; ++rt) {
                #pragma unroll
                for (int dt = 0; dt < 4; ++dt)
                    #pragma unroll
                    for (int r = 0; r < 4; ++r)
                        base[(rt * 16 + 4 * q + r) * 64 + dt * 16 + i16] = acc[rt][dt][r];
                if (i16 == 0) {
                    #pragma unroll
                    for (int r = 0; r < 4; ++r) base[4096 + rt * 16 + 4 * q + r] = lsum[rt][r];
                }
            }
        }
        __syncthreads();
        if (w < step) {
            const float* base = sF + w * 4160;
            #pragma unroll
            for (int rt = 0; rt < 4; ++rt) {
                #pragma unroll
                for (int dt = 0; dt < 4; ++dt)
                    #pragma unroll
                    for (int r = 0; r < 4; ++r)
                        acc[rt][dt][r] += base[(rt * 16 + 4 * q + r) * 64 + dt * 16 + i16];
                #pragma unroll
                for (int r = 0; r < 4; ++r) lsum[rt][r] += base[4096 + rt * 16 + 4 * q + r];
            }
        }
        __syncthreads();
    }

    // ---- wave 0 writes the block's (O,l) partial to global ----
    if (w == 0) {
        #pragma unroll
        for (int rt = 0; rt < 4; ++rt) {
            #pragma unroll
            for (int dt = 0; dt < 4; ++dt)
                #pragma unroll
                for (int r = 0; r < 4; ++r) {
                    const int row = qb0 + rt * 16 + 4 * q + r;
                    Opart[((size_t)kh * 8192 + row) * 64 + dt * 16 + i16] = acc[rt][dt][r];
                }
            if (i16 == 0) {
                #pragma unroll
                for (int r = 0; r < 4; ++r)
                    Lpart[kh * 8192 + qb0 + rt * 16 + 4 * q + r] = lsum[rt][r];
            }
        }
    }
}

// ---- merge: O = (O0 + O1) / (l0 + l1) ----
__global__ __launch_bounds__(256)
void merge(const float* __restrict__ Opart, const float* __restrict__ Lpart,
           float* __restrict__ Og) {
    const int idx = blockIdx.x * 256 + threadIdx.x;   // 0..131071
    const int row = idx >> 4, seg = idx & 15;
    const float4 a = *(const float4*)(Opart + (size_t)row * 64 + seg * 4);
    const float4 b = *(const float4*)(Opart + ((size_t)8192 + row) * 64 + seg * 4);
    const float inv = 1.0f / (Lpart[row] + Lpart[8192 + row]);
    float4 o;
    o.x = (a.x + b.x) * inv;
    o.y = (a.y + b.y) * inv;
    o.z = (a.z + b.z) * inv;
    o.w = (a.w + b.w) * inv;
    *(float4*)(Og + (size_t)row * 64 + seg * 4) = o;
}

extern "C" void kernel_launch(void* const* d_in, const int* in_sizes, int n_in,
                              void* d_out, int out_size, void* d_ws, size_t ws_size,
                              hipStream_t stream) {
    const float* Q = (const float*)d_in[0];
    const float* K = (const float*)d_in[1];
    const float* V = (const float*)d_in[2];
    float* O = (float*)d_out;
    char* ws = (char*)d_ws;
    uint4* Kb4   = (uint4*)ws;                        // 1 MB, fragment-linear
    uint4* Vt4   = (uint4*)(ws + (1 << 20));          // 1 MB, fragment-linear
    float* Opart = (float*)(ws + (2 << 20));          // 2 x 8192 x 64 fp32 = 4 MB
    float* Lpart = (float*)(ws + (6 << 20));          // 2 x 8192 fp32
    hipLaunchKernelGGL(prepass, dim3(512), dim3(256), 0, stream, K, V, Kb4, Vt4);
    hipLaunchKernelGGL(attn_main, dim3(256), dim3(512), 0, stream, Q, Kb4, Vt4, Opart, Lpart);
    hipLaunchKernelGGL(merge, dim3(512), dim3(256), 0, stream, Opart, Lpart, O);
}